// Round 1
// baseline (512.090 us; speedup 1.0000x reference)
//
#include <hip/hip_runtime.h>
#include <hip/hip_bf16.h>

// Problem constants
#define HH   16
#define DD   64
#define HSZ  1024
#define BB   8
#define SS   1024
#define NTOK (BB*SS)   // 8192

typedef __attribute__((ext_vector_type(8))) short bf16x8;
typedef __attribute__((ext_vector_type(4))) float f32x4;
typedef unsigned short u16;

__device__ __forceinline__ short f2bf(float x) {
    union { float f; unsigned u; } v; v.f = x;
    unsigned r = (v.u + 0x7fffu + ((v.u >> 16) & 1u)) >> 16;
    return (short)r;
}

// ---------------------------------------------------------------------------
// Mask format detection: mask may arrive as int8/bool (1B) or int32 (4B).
// If int32 with values {0,1}, every byte at idx%4!=0 in the first 8192 bytes
// is zero. Random 0/1 bytes would make that probability ~2^-6144.
// ---------------------------------------------------------------------------
__global__ void detect_mask_kernel(const unsigned char* mask_bytes, int* flag) {
    __shared__ int nz;
    if (threadIdx.x == 0) nz = 0;
    __syncthreads();
    int cnt = 0;
    for (int i = threadIdx.x; i < BB * SS; i += blockDim.x)
        if ((i & 3) && mask_bytes[i]) cnt++;
    if (cnt) atomicAdd(&nz, cnt);
    __syncthreads();
    if (threadIdx.x == 0) flag[0] = (nz > 0) ? 1 : 0;  // 1 = byte format
}

__global__ void mask_bias_kernel(const void* mask, const int* flag, float* bias) {
    int i = blockIdx.x * blockDim.x + threadIdx.x;
    if (i >= BB * SS) return;
    bool m;
    if (flag[0]) m = ((const unsigned char*)mask)[i] != 0;
    else         m = ((const int*)mask)[i] != 0;
    bias[i] = m ? -1e9f : 0.0f;   // reference: where(mask, -1e9, scores)
}

// ---------------------------------------------------------------------------
// Projection GEMM: Y = X @ W^T + b.   M=8192, N=1024, K=1024.
// BM=BN=64, BK=32. 256 threads = 4 waves; wave w computes rows [16w,16w+16) x 64 cols.
// MODE 0: Q -> bf16 [B,H,S,D], scaled by 1/8 (folds 1/sqrt(D) into Q)
// MODE 1: K -> bf16 [B,H,S,D]
// MODE 2: V -> bf16 [B,H,D,S]  (transposed so PV B-frag is contiguous)
// MODE 3: ctx(bf16) @ Wo^T + bo -> f32 [B,S,HS] (d_out)
// ---------------------------------------------------------------------------
template<int MODE>
__global__ __launch_bounds__(256) void proj_kernel(const void* __restrict__ Xv,
                                                   const float* __restrict__ W,
                                                   const float* __restrict__ bias,
                                                   void* __restrict__ Yv) {
    const int bm = blockIdx.x;   // 0..127
    const int bn = blockIdx.y;   // 0..15
    const int tid  = threadIdx.x;
    const int wave = tid >> 6;
    const int lane = tid & 63;
    const int l15  = lane & 15;
    const int g    = lane >> 4;

    // +8 shorts pad (16B) keeps 16B alignment for ds_read_b128, spreads banks
    __shared__ short Xs[64][40];
    __shared__ short Ws[64][40];

    f32x4 acc[4] = {};   // 4 col-tiles of 16

    const int srow = tid >> 2;        // 0..63
    const int sc8  = (tid & 3) * 8;   // 0,8,16,24

    for (int k0 = 0; k0 < HSZ; k0 += 32) {
        // ---- stage X tile (64 x 32) ----
        if constexpr (MODE == 3) {
            const u16* X = (const u16*)Xv;
            bf16x8 xv = *(const bf16x8*)&X[(size_t)(bm * 64 + srow) * HSZ + k0 + sc8];
            *(bf16x8*)&Xs[srow][sc8] = xv;
        } else {
            const float* X = (const float*)Xv;
            size_t base = (size_t)(bm * 64 + srow) * HSZ + k0 + sc8;
            f32x4 x0 = *(const f32x4*)&X[base];
            f32x4 x1 = *(const f32x4*)&X[base + 4];
            union { bf16x8 v; short s[8]; } xv;
            xv.s[0] = f2bf(x0[0]); xv.s[1] = f2bf(x0[1]); xv.s[2] = f2bf(x0[2]); xv.s[3] = f2bf(x0[3]);
            xv.s[4] = f2bf(x1[0]); xv.s[5] = f2bf(x1[1]); xv.s[6] = f2bf(x1[2]); xv.s[7] = f2bf(x1[3]);
            *(bf16x8*)&Xs[srow][sc8] = xv.v;
        }
        // ---- stage W tile (64 out-cols x 32 k) ----
        {
            size_t base = (size_t)(bn * 64 + srow) * HSZ + k0 + sc8;
            f32x4 w0 = *(const f32x4*)&W[base];
            f32x4 w1 = *(const f32x4*)&W[base + 4];
            union { bf16x8 v; short s[8]; } wv;
            wv.s[0] = f2bf(w0[0]); wv.s[1] = f2bf(w0[1]); wv.s[2] = f2bf(w0[2]); wv.s[3] = f2bf(w0[3]);
            wv.s[4] = f2bf(w1[0]); wv.s[5] = f2bf(w1[1]); wv.s[6] = f2bf(w1[2]); wv.s[7] = f2bf(w1[3]);
            *(bf16x8*)&Ws[srow][sc8] = wv.v;
        }
        __syncthreads();

        bf16x8 a = *(const bf16x8*)&Xs[wave * 16 + l15][g * 8];
#pragma unroll
        for (int ct = 0; ct < 4; ++ct) {
            bf16x8 b = *(const bf16x8*)&Ws[ct * 16 + l15][g * 8];
            acc[ct] = __builtin_amdgcn_mfma_f32_16x16x32_bf16(a, b, acc[ct], 0, 0, 0);
        }
        __syncthreads();
    }

    // ---- epilogue ----
#pragma unroll
    for (int ct = 0; ct < 4; ++ct) {
        const int o  = bn * 64 + ct * 16 + l15;
        const float bv = bias[o];
#pragma unroll
        for (int r = 0; r < 4; ++r) {
            const int n = bm * 64 + wave * 16 + g * 4 + r;
            float y = acc[ct][r] + bv;
            if constexpr (MODE == 0) {
                int b_ = n >> 10, s = n & 1023, h_ = o >> 6, d = o & 63;
                ((u16*)Yv)[(((size_t)b_ * HH + h_) * SS + s) * DD + d] = (u16)f2bf(y * 0.125f);
            } else if constexpr (MODE == 1) {
                int b_ = n >> 10, s = n & 1023, h_ = o >> 6, d = o & 63;
                ((u16*)Yv)[(((size_t)b_ * HH + h_) * SS + s) * DD + d] = (u16)f2bf(y);
            } else if constexpr (MODE == 2) {
                int b_ = n >> 10, s = n & 1023, h_ = o >> 6, d = o & 63;
                ((u16*)Yv)[(((size_t)b_ * HH + h_) * DD + d) * SS + s] = (u16)f2bf(y);
            } else {
                ((float*)Yv)[(size_t)n * HSZ + o] = y;
            }
        }
    }
}

// ---------------------------------------------------------------------------
// Attention: one block per (b, h, 16-row q-tile). 256 threads = 4 waves.
// Phase 1: scores[16][1024] f32 in LDS (wave w covers keys [256w,256w+256)).
// Phase 2: block softmax with mask bias (16 threads per row).
// Phase 3: PV — wave w computes out cols [16w,16w+16), K=1024 in steps of 32.
// ---------------------------------------------------------------------------
__global__ __launch_bounds__(256) void attn_kernel(const u16* __restrict__ Qh,
                                                   const u16* __restrict__ Kh,
                                                   const u16* __restrict__ Vt,
                                                   const float* __restrict__ bias,
                                                   u16* __restrict__ ctx) {
    const int qt = blockIdx.x;   // 0..63
    const int h  = blockIdx.y;   // 0..15
    const int b  = blockIdx.z;   // 0..7
    const int bh = b * HH + h;
    const int q0 = qt * 16;

    const int tid  = threadIdx.x;
    const int wave = tid >> 6;
    const int lane = tid & 63;
    const int l15  = lane & 15;
    const int g    = lane >> 4;

    __shared__ float Sc[16][1024];   // 64 KB

    const u16* Qbase = Qh + ((size_t)bh * SS + q0) * DD;
    const u16* Kbase = Kh + (size_t)bh * SS * DD;
    const u16* Vbase = Vt + (size_t)bh * DD * SS;
    const float* brow = bias + b * SS;

    // Q fragments for this q-tile (reused across all key tiles)
    bf16x8 qa0 = *(const bf16x8*)&Qbase[(size_t)l15 * DD + g * 8];
    bf16x8 qa1 = *(const bf16x8*)&Qbase[(size_t)l15 * DD + 32 + g * 8];

    // ---- phase 1: scores ----
    for (int kt = 0; kt < 16; ++kt) {
        const int key0 = wave * 256 + kt * 16;
        f32x4 s = {};
        bf16x8 kb0 = *(const bf16x8*)&Kbase[(size_t)(key0 + l15) * DD + g * 8];
        bf16x8 kb1 = *(const bf16x8*)&Kbase[(size_t)(key0 + l15) * DD + 32 + g * 8];
        s = __builtin_amdgcn_mfma_f32_16x16x32_bf16(qa0, kb0, s, 0, 0, 0);
        s = __builtin_amdgcn_mfma_f32_16x16x32_bf16(qa1, kb1, s, 0, 0, 0);
#pragma unroll
        for (int r = 0; r < 4; ++r)
            Sc[g * 4 + r][key0 + l15] = s[r];
    }
    __syncthreads();

    // ---- phase 2: softmax (row = tid>>4 handled by 16 threads) ----
    {
        const int row = tid >> 4;
        const int i0  = tid & 15;
        float m = -1e30f;
        for (int j = 0; j < 64; ++j) {
            int c = i0 + 16 * j;
            m = fmaxf(m, Sc[row][c] + brow[c]);
        }
        for (int w2 = 1; w2 < 16; w2 <<= 1) m = fmaxf(m, __shfl_xor(m, w2));
        float sum = 0.0f;
        for (int j = 0; j < 64; ++j) {
            int c = i0 + 16 * j;
            float e = __expf(Sc[row][c] + brow[c] - m);
            Sc[row][c] = e;
            sum += e;
        }
        for (int w2 = 1; w2 < 16; w2 <<= 1) sum += __shfl_xor(sum, w2);
        float inv = 1.0f / sum;
        for (int j = 0; j < 64; ++j) Sc[row][i0 + 16 * j] *= inv;
    }
    __syncthreads();

    // ---- phase 3: PV ----
    const int d0 = wave * 16;
    f32x4 o = {};
    for (int k0 = 0; k0 < SS; k0 += 32) {
        f32x4 p0 = *(const f32x4*)&Sc[l15][k0 + g * 8];
        f32x4 p1 = *(const f32x4*)&Sc[l15][k0 + g * 8 + 4];
        union { bf16x8 v; short s[8]; } pa;
        pa.s[0] = f2bf(p0[0]); pa.s[1] = f2bf(p0[1]); pa.s[2] = f2bf(p0[2]); pa.s[3] = f2bf(p0[3]);
        pa.s[4] = f2bf(p1[0]); pa.s[5] = f2bf(p1[1]); pa.s[6] = f2bf(p1[2]); pa.s[7] = f2bf(p1[3]);
        bf16x8 vb = *(const bf16x8*)&Vbase[(size_t)(d0 + l15) * SS + k0 + g * 8];
        o = __builtin_amdgcn_mfma_f32_16x16x32_bf16(pa.v, vb, o, 0, 0, 0);
    }
#pragma unroll
    for (int r = 0; r < 4; ++r) {
        const int n   = b * SS + q0 + g * 4 + r;
        const int col = h * DD + d0 + l15;
        ctx[(size_t)n * HSZ + col] = (u16)f2bf(o[r]);
    }
}

// ---------------------------------------------------------------------------
extern "C" void kernel_launch(void* const* d_in, const int* in_sizes, int n_in,
                              void* d_out, int out_size, void* d_ws, size_t ws_size,
                              hipStream_t stream) {
    const float* v    = (const float*)d_in[0];
    const float* k    = (const float*)d_in[1];
    const float* q    = (const float*)d_in[2];
    const void*  mask = d_in[3];
    const float* Wq = (const float*)d_in[4];
    const float* bq = (const float*)d_in[5];
    const float* Wk = (const float*)d_in[6];
    const float* bk = (const float*)d_in[7];
    const float* Wv = (const float*)d_in[8];
    const float* bv = (const float*)d_in[9];
    const float* Wo = (const float*)d_in[10];
    const float* bo = (const float*)d_in[11];

    char* ws = (char*)d_ws;
    float* bias = (float*)ws;                       // 32 KB
    int*   flag = (int*)(ws + 32768);               // 4 B
    u16*   Qh   = (u16*)(ws + 65536);               // 16 MB each
    u16*   Kh   = Qh + (size_t)BB * HH * SS * DD;
    u16*   Vt   = Kh + (size_t)BB * HH * SS * DD;
    u16*   ctx  = Vt + (size_t)BB * HH * SS * DD;

    detect_mask_kernel<<<1, 256, 0, stream>>>((const unsigned char*)mask, flag);
    mask_bias_kernel<<<32, 256, 0, stream>>>(mask, flag, bias);

    dim3 pgrid(NTOK / 64, HSZ / 64);   // (128, 16)
    proj_kernel<0><<<pgrid, 256, 0, stream>>>(q, Wq, bq, Qh);
    proj_kernel<1><<<pgrid, 256, 0, stream>>>(k, Wk, bk, Kh);
    proj_kernel<2><<<pgrid, 256, 0, stream>>>(v, Wv, bv, Vt);

    dim3 agrid(SS / 16, HH, BB);       // (64, 16, 8)
    attn_kernel<<<agrid, 256, 0, stream>>>(Qh, Kh, Vt, bias, ctx);

    proj_kernel<3><<<pgrid, 256, 0, stream>>>(ctx, Wo, bo, (float*)d_out);
}

// Round 2
// 397.370 us; speedup vs baseline: 1.2887x; 1.2887x over previous
//
#include <hip/hip_runtime.h>
#include <hip/hip_bf16.h>

// Problem constants
#define HH   16
#define DD   64
#define HSZ  1024
#define BB   8
#define SS   1024
#define NTOK (BB*SS)   // 8192

typedef __attribute__((ext_vector_type(8))) short bf16x8;
typedef __attribute__((ext_vector_type(4))) float f32x4;
typedef unsigned short u16;
typedef __attribute__((ext_vector_type(4))) unsigned short u16x4;

__device__ __forceinline__ u16 bfc(float x) {
    __hip_bfloat16 h = __float2bfloat16(x);   // RNE; compiler pairs into v_cvt_pk_bf16_f32
    return *(u16*)&h;
}

// ---------------------------------------------------------------------------
// Mask format detection (bool may arrive as int8 or int32).
// ---------------------------------------------------------------------------
__global__ void detect_mask_kernel(const unsigned char* mask_bytes, int* flag) {
    __shared__ int nz;
    if (threadIdx.x == 0) nz = 0;
    __syncthreads();
    int cnt = 0;
    for (int i = threadIdx.x; i < BB * SS; i += blockDim.x)
        if ((i & 3) && mask_bytes[i]) cnt++;
    if (cnt) atomicAdd(&nz, cnt);
    __syncthreads();
    if (threadIdx.x == 0) flag[0] = (nz > 0) ? 1 : 0;  // 1 = byte format
}

__global__ void mask_bias_kernel(const void* mask, const int* flag, float* bias) {
    int i = blockIdx.x * blockDim.x + threadIdx.x;
    if (i >= BB * SS) return;
    bool m;
    if (flag[0]) m = ((const unsigned char*)mask)[i] != 0;
    else         m = ((const int*)mask)[i] != 0;
    bias[i] = m ? -1e9f : 0.0f;   // reference: where(mask, -1e9, scores)
}

// ---------------------------------------------------------------------------
// Projection GEMM: Y = X @ W^T + b.   M=8192, N=1024, K=1024.
// BM=BN=128, BK=32. 256 threads = 4 waves in 2x2; each wave owns 64x64 (4x4 frags).
// MODE 0: Q -> bf16 [B,H,S,D], scaled by 1/8 (folds 1/sqrt(D))
// MODE 1: K -> bf16 [B,H,S,D]
// MODE 2: V -> bf16 [B,H,D,S]  (transposed so PV B-frag reads contiguous)
// MODE 3: ctx(bf16) @ Wo^T + bo -> f32 [B,S,HS] (d_out)
// ---------------------------------------------------------------------------
template<int MODE>
__global__ __launch_bounds__(256) void proj_kernel(const void* __restrict__ Xv,
                                                   const float* __restrict__ W,
                                                   const float* __restrict__ bias,
                                                   void* __restrict__ Yv) {
    const int bm = blockIdx.x;   // 0..63
    const int bn = blockIdx.y;   // 0..7
    const int tid  = threadIdx.x;
    const int wave = tid >> 6;
    const int lane = tid & 63;
    const int l15  = lane & 15;
    const int g    = lane >> 4;
    const int wr   = wave >> 1;   // 0..1
    const int wc   = wave & 1;    // 0..1

    // 40-short rows: 16B-aligned, stride 20 words -> slot (5*row+g) mod 8, even spread
    __shared__ u16 Xs[128][40];
    __shared__ u16 Ws[128][40];

    f32x4 acc[4][4] = {};

    const int r0 = tid >> 2;        // 0..63
    const int c8 = (tid & 3) * 8;   // 0,8,16,24

    for (int k0 = 0; k0 < HSZ; k0 += 32) {
#pragma unroll
        for (int half = 0; half < 2; ++half) {
            const int row = r0 + half * 64;
            if constexpr (MODE == 3) {
                const u16* X = (const u16*)Xv;
                *(bf16x8*)&Xs[row][c8] =
                    *(const bf16x8*)&X[(size_t)(bm * 128 + row) * HSZ + k0 + c8];
            } else {
                const float* X = (const float*)Xv;
                size_t base = (size_t)(bm * 128 + row) * HSZ + k0 + c8;
                f32x4 x0 = *(const f32x4*)&X[base];
                f32x4 x1 = *(const f32x4*)&X[base + 4];
                union { bf16x8 v; u16 s[8]; } t;
#pragma unroll
                for (int e = 0; e < 4; ++e) { t.s[e] = bfc(x0[e]); t.s[4 + e] = bfc(x1[e]); }
                *(bf16x8*)&Xs[row][c8] = t.v;
            }
            {
                size_t base = (size_t)(bn * 128 + row) * HSZ + k0 + c8;
                f32x4 w0 = *(const f32x4*)&W[base];
                f32x4 w1 = *(const f32x4*)&W[base + 4];
                union { bf16x8 v; u16 s[8]; } t;
#pragma unroll
                for (int e = 0; e < 4; ++e) { t.s[e] = bfc(w0[e]); t.s[4 + e] = bfc(w1[e]); }
                *(bf16x8*)&Ws[row][c8] = t.v;
            }
        }
        __syncthreads();

        bf16x8 a[4], bb[4];
#pragma unroll
        for (int m = 0; m < 4; ++m) a[m]  = *(const bf16x8*)&Xs[wr * 64 + m * 16 + l15][g * 8];
#pragma unroll
        for (int n = 0; n < 4; ++n) bb[n] = *(const bf16x8*)&Ws[wc * 64 + n * 16 + l15][g * 8];
#pragma unroll
        for (int m = 0; m < 4; ++m)
#pragma unroll
            for (int n = 0; n < 4; ++n)
                acc[m][n] = __builtin_amdgcn_mfma_f32_16x16x32_bf16(a[m], bb[n], acc[m][n], 0, 0, 0);
        __syncthreads();
    }

    // ---- epilogue ----
#pragma unroll
    for (int m = 0; m < 4; ++m) {
#pragma unroll
        for (int n = 0; n < 4; ++n) {
            const int o = bn * 128 + wc * 64 + n * 16 + l15;
            const float bvv = bias[o];
#pragma unroll
            for (int r = 0; r < 4; ++r) {
                const int nrow = bm * 128 + wr * 64 + m * 16 + g * 4 + r;
                float y = acc[m][n][r] + bvv;
                if constexpr (MODE == 0) {
                    int b_ = nrow >> 10, s = nrow & 1023, h_ = o >> 6, d = o & 63;
                    ((u16*)Yv)[(((size_t)b_ * HH + h_) * SS + s) * DD + d] = bfc(y * 0.125f);
                } else if constexpr (MODE == 1) {
                    int b_ = nrow >> 10, s = nrow & 1023, h_ = o >> 6, d = o & 63;
                    ((u16*)Yv)[(((size_t)b_ * HH + h_) * SS + s) * DD + d] = bfc(y);
                } else if constexpr (MODE == 2) {
                    int b_ = nrow >> 10, s = nrow & 1023, h_ = o >> 6, d = o & 63;
                    ((u16*)Yv)[(((size_t)b_ * HH + h_) * DD + d) * SS + s] = bfc(y);
                } else {
                    ((float*)Yv)[(size_t)nrow * HSZ + o] = y;
                }
            }
        }
    }
}

// ---------------------------------------------------------------------------
// Attention: one block per (b, h, 16-query tile). 256 threads = 4 waves.
// Swapped QK^T: s = mfma(K_frag, Q_frag) -> lane (g,l15) holds
// score[key = wbase + kt*16 + g*4 + r][q = l15] entirely in registers (s[16] f32x4).
// Softmax: in-register max/sum + shfl over g + tiny LDS cross-wave exchange.
// P~ = exp(s - m_global), unnormalized, -> per-wave bf16 LDS (padded rows).
// PV: wave computes partial over its 256 keys for all 64 d; cross-wave LDS reduce,
// normalization (1/sum) folded into epilogue.
// ---------------------------------------------------------------------------
__global__ __launch_bounds__(256) void attn_kernel(const u16* __restrict__ Qh,
                                                   const u16* __restrict__ Kh,
                                                   const u16* __restrict__ Vt,
                                                   const float* __restrict__ bias,
                                                   u16* __restrict__ ctx) {
    const int qt = blockIdx.x;   // 0..63
    const int h  = blockIdx.y;   // 0..15
    const int b  = blockIdx.z;   // 0..7
    const int bh = b * HH + h;
    const int q0 = qt * 16;

    const int tid  = threadIdx.x;
    const int wave = tid >> 6;
    const int lane = tid & 63;
    const int l15  = lane & 15;
    const int g    = lane >> 4;

    __shared__ u16   Pl[4][16][264];   // 33792 B, pad->even bank spread
    __shared__ float red[4][16][68];   // 17408 B (bias_s overlays; dead by then)
    __shared__ float wmax[4][16];
    __shared__ float wsum[4][16];

    float* bias_s = &red[0][0][0];     // 1024 floats, used only in QK phase

    const int key_base = wave * 256;

    // stage this wave's bias slice (no cross-wave dependency)
    {
        const float* brow = bias + b * SS;
        *(f32x4*)&bias_s[key_base + lane * 4] = *(const f32x4*)&brow[key_base + lane * 4];
    }

    const u16* Qbase = Qh + ((size_t)bh * SS + q0) * DD;
    const u16* Kbase = Kh + (size_t)bh * SS * DD;
    const u16* Vbase = Vt + (size_t)bh * DD * SS;

    // Q fragments (B-operand of swapped MFMA): lane supplies Q[q0+l15][g*8..+8]
    bf16x8 qa0 = *(const bf16x8*)&Qbase[(size_t)l15 * DD + g * 8];
    bf16x8 qa1 = *(const bf16x8*)&Qbase[(size_t)l15 * DD + 32 + g * 8];

    // ---- QK^T (swapped): s[kt][r] = score(key_base+kt*16+g*4+r, q0+l15) ----
    f32x4 s[16];
#pragma unroll
    for (int kt = 0; kt < 16; ++kt) {
        const int key0 = key_base + kt * 16;
        bf16x8 kb0 = *(const bf16x8*)&Kbase[(size_t)(key0 + l15) * DD + g * 8];
        bf16x8 kb1 = *(const bf16x8*)&Kbase[(size_t)(key0 + l15) * DD + 32 + g * 8];
        f32x4 acc0 = {};
        acc0 = __builtin_amdgcn_mfma_f32_16x16x32_bf16(kb0, qa0, acc0, 0, 0, 0);
        acc0 = __builtin_amdgcn_mfma_f32_16x16x32_bf16(kb1, qa1, acc0, 0, 0, 0);
        s[kt] = acc0;
    }

    // ---- bias + row max (q = l15 is lane-local) ----
    float m = -3e38f;
#pragma unroll
    for (int kt = 0; kt < 16; ++kt) {
        const int kb = key_base + kt * 16 + g * 4;
#pragma unroll
        for (int r = 0; r < 4; ++r) {
            s[kt][r] += bias_s[kb + r];
            m = fmaxf(m, s[kt][r]);
        }
    }
    m = fmaxf(m, __shfl_xor(m, 16));
    m = fmaxf(m, __shfl_xor(m, 32));
    if (g == 0) wmax[wave][l15] = m;
    __syncthreads();
    m = fmaxf(fmaxf(wmax[0][l15], wmax[1][l15]), fmaxf(wmax[2][l15], wmax[3][l15]));

    // ---- exp, P~ -> LDS (bf16), local sum ----
    float lsum = 0.0f;
#pragma unroll
    for (int kt = 0; kt < 16; ++kt) {
        union { u16x4 v; u16 u[4]; } pw;
#pragma unroll
        for (int r = 0; r < 4; ++r) {
            float e = __expf(s[kt][r] - m);
            lsum += e;
            pw.u[r] = bfc(e);
        }
        *(u16x4*)&Pl[wave][l15][kt * 16 + g * 4] = pw.v;
    }
    lsum += __shfl_xor(lsum, 16);
    lsum += __shfl_xor(lsum, 32);
    if (g == 0) wsum[wave][l15] = lsum;
    // no sync needed: Pl is read only by the writing wave; wsum read after the
    // __syncthreads below.

    // ---- PV: partial over this wave's 256 keys, all 64 d ----
    f32x4 o[4] = {};
#pragma unroll
    for (int k0 = 0; k0 < 256; k0 += 32) {
        bf16x8 pa = *(const bf16x8*)&Pl[wave][l15][k0 + g * 8];
#pragma unroll
        for (int dt = 0; dt < 4; ++dt) {
            bf16x8 vb = *(const bf16x8*)
                &Vbase[(size_t)(dt * 16 + l15) * SS + key_base + k0 + g * 8];
            o[dt] = __builtin_amdgcn_mfma_f32_16x16x32_bf16(pa, vb, o[dt], 0, 0, 0);
        }
    }

    // ---- cross-wave reduce ----
#pragma unroll
    for (int dt = 0; dt < 4; ++dt)
#pragma unroll
        for (int r = 0; r < 4; ++r)
            red[wave][g * 4 + r][dt * 16 + l15] = o[dt][r];
    __syncthreads();

    {
        const int q  = tid >> 4;          // 0..15
        const int d0 = (tid & 15) * 4;    // 0..60
        const float inv = 1.0f / (wsum[0][q] + wsum[1][q] + wsum[2][q] + wsum[3][q]);
        union { u16x4 v; u16 u[4]; } w4;
#pragma unroll
        for (int e = 0; e < 4; ++e) {
            float t = red[0][q][d0 + e] + red[1][q][d0 + e] +
                      red[2][q][d0 + e] + red[3][q][d0 + e];
            w4.u[e] = bfc(t * inv);
        }
        *(u16x4*)&ctx[(size_t)(b * SS + q0 + q) * HSZ + h * DD + d0] = w4.v;
    }
}

// ---------------------------------------------------------------------------
extern "C" void kernel_launch(void* const* d_in, const int* in_sizes, int n_in,
                              void* d_out, int out_size, void* d_ws, size_t ws_size,
                              hipStream_t stream) {
    const float* v    = (const float*)d_in[0];
    const float* k    = (const float*)d_in[1];
    const float* q    = (const float*)d_in[2];
    const void*  mask = d_in[3];
    const float* Wq = (const float*)d_in[4];
    const float* bq = (const float*)d_in[5];
    const float* Wk = (const float*)d_in[6];
    const float* bk = (const float*)d_in[7];
    const float* Wv = (const float*)d_in[8];
    const float* bv = (const float*)d_in[9];
    const float* Wo = (const float*)d_in[10];
    const float* bo = (const float*)d_in[11];

    char* ws = (char*)d_ws;
    float* bias = (float*)ws;                       // 32 KB
    int*   flag = (int*)(ws + 32768);               // 4 B
    u16*   Qh   = (u16*)(ws + 65536);               // 16 MB each
    u16*   Kh   = Qh + (size_t)BB * HH * SS * DD;
    u16*   Vt   = Kh + (size_t)BB * HH * SS * DD;
    u16*   ctx  = Vt + (size_t)BB * HH * SS * DD;

    detect_mask_kernel<<<1, 256, 0, stream>>>((const unsigned char*)mask, flag);
    mask_bias_kernel<<<32, 256, 0, stream>>>(mask, flag, bias);

    dim3 pgrid(NTOK / 128, HSZ / 128);   // (64, 8)
    proj_kernel<0><<<pgrid, 256, 0, stream>>>(q, Wq, bq, Qh);
    proj_kernel<1><<<pgrid, 256, 0, stream>>>(k, Wk, bk, Kh);
    proj_kernel<2><<<pgrid, 256, 0, stream>>>(v, Wv, bv, Vt);

    dim3 agrid(SS / 16, HH, BB);         // (64, 16, 8)
    attn_kernel<<<agrid, 256, 0, stream>>>(Qh, Kh, Vt, bias, ctx);

    proj_kernel<3><<<pgrid, 256, 0, stream>>>(ctx, Wo, bo, (float*)d_out);
}

// Round 3
// 275.187 us; speedup vs baseline: 1.8609x; 1.4440x over previous
//
#include <hip/hip_runtime.h>
#include <hip/hip_bf16.h>

// Problem constants
#define HH   16
#define DD   64
#define HSZ  1024
#define BB   8
#define SS   1024
#define NTOK (BB*SS)   // 8192

typedef __attribute__((ext_vector_type(8))) short bf16x8;
typedef __attribute__((ext_vector_type(4))) float f32x4;
typedef unsigned short u16;
typedef __attribute__((ext_vector_type(4))) unsigned short u16x4;

__device__ __forceinline__ u16 bfc(float x) {
    __hip_bfloat16 h = __float2bfloat16(x);   // RNE; pairs into v_cvt_pk_bf16_f32
    return *(u16*)&h;
}

// ---------------------------------------------------------------------------
// Mask -> additive bias, with on-device format detection (bool may arrive as
// int8 or int32). Single block: detect (int32 => bytes at idx%4!=0 are 0),
// then write bias[i] = mask ? -1e9 : 0.
// ---------------------------------------------------------------------------
__global__ void mask_bias_kernel(const void* mask, float* bias) {
    __shared__ int fmt;   // 1 = byte format
    const unsigned char* mb = (const unsigned char*)mask;
    if (threadIdx.x == 0) fmt = 0;
    __syncthreads();
    int nz = 0;
    for (int i = threadIdx.x; i < BB * SS; i += blockDim.x)
        if ((i & 3) && mb[i]) nz = 1;
    if (nz) fmt = 1;      // benign race: all writers store 1
    __syncthreads();
    const int f = fmt;
    for (int i = threadIdx.x; i < BB * SS; i += blockDim.x) {
        bool m = f ? (mb[i] != 0) : (((const int*)mask)[i] != 0);
        bias[i] = m ? -1e9f : 0.0f;
    }
}

// ---------------------------------------------------------------------------
// Projection GEMM: Y = X @ W^T + b.   M=8192, N=1024, K=1024.
// BM=BN=128, BK=32. 256 threads = 4 waves in 2x2; each wave owns 64x64.
// MODE 0: Q -> bf16 [B,H,S,D], scaled by 1/8 (folds 1/sqrt(D))
// MODE 1: K -> bf16 [B,H,S,D]
// MODE 2: V -> bf16 [B,H,D,S]  (transposed so PV B-frag reads contiguous)
// MODE 3: ctx(bf16) @ Wo^T + bo -> f32 [B,S,HS] (d_out)
// ---------------------------------------------------------------------------
template<int MODE>
__global__ __launch_bounds__(256) void proj_kernel(const void* __restrict__ Xv,
                                                   const float* __restrict__ W,
                                                   const float* __restrict__ bias,
                                                   void* __restrict__ Yv) {
    const int bm = blockIdx.x;
    const int bn = blockIdx.y;
    const int tid  = threadIdx.x;
    const int wave = tid >> 6;
    const int lane = tid & 63;
    const int l15  = lane & 15;
    const int g    = lane >> 4;
    const int wr   = wave >> 1;
    const int wc   = wave & 1;

    __shared__ u16 Xs[128][40];
    __shared__ u16 Ws[128][40];

    f32x4 acc[4][4] = {};

    const int r0 = tid >> 2;
    const int c8 = (tid & 3) * 8;

    for (int k0 = 0; k0 < HSZ; k0 += 32) {
#pragma unroll
        for (int half = 0; half < 2; ++half) {
            const int row = r0 + half * 64;
            if constexpr (MODE == 3) {
                const u16* X = (const u16*)Xv;
                *(bf16x8*)&Xs[row][c8] =
                    *(const bf16x8*)&X[(size_t)(bm * 128 + row) * HSZ + k0 + c8];
            } else {
                const float* X = (const float*)Xv;
                size_t base = (size_t)(bm * 128 + row) * HSZ + k0 + c8;
                f32x4 x0 = *(const f32x4*)&X[base];
                f32x4 x1 = *(const f32x4*)&X[base + 4];
                union { bf16x8 v; u16 s[8]; } t;
#pragma unroll
                for (int e = 0; e < 4; ++e) { t.s[e] = bfc(x0[e]); t.s[4 + e] = bfc(x1[e]); }
                *(bf16x8*)&Xs[row][c8] = t.v;
            }
            {
                size_t base = (size_t)(bn * 128 + row) * HSZ + k0 + c8;
                f32x4 w0 = *(const f32x4*)&W[base];
                f32x4 w1 = *(const f32x4*)&W[base + 4];
                union { bf16x8 v; u16 s[8]; } t;
#pragma unroll
                for (int e = 0; e < 4; ++e) { t.s[e] = bfc(w0[e]); t.s[4 + e] = bfc(w1[e]); }
                *(bf16x8*)&Ws[row][c8] = t.v;
            }
        }
        __syncthreads();

        bf16x8 a[4], bb[4];
#pragma unroll
        for (int m = 0; m < 4; ++m) a[m]  = *(const bf16x8*)&Xs[wr * 64 + m * 16 + l15][g * 8];
#pragma unroll
        for (int n = 0; n < 4; ++n) bb[n] = *(const bf16x8*)&Ws[wc * 64 + n * 16 + l15][g * 8];
#pragma unroll
        for (int m = 0; m < 4; ++m)
#pragma unroll
            for (int n = 0; n < 4; ++n)
                acc[m][n] = __builtin_amdgcn_mfma_f32_16x16x32_bf16(a[m], bb[n], acc[m][n], 0, 0, 0);
        __syncthreads();
    }

#pragma unroll
    for (int m = 0; m < 4; ++m) {
#pragma unroll
        for (int n = 0; n < 4; ++n) {
            const int o = bn * 128 + wc * 64 + n * 16 + l15;
            const float bvv = bias[o];
#pragma unroll
            for (int r = 0; r < 4; ++r) {
                const int nrow = bm * 128 + wr * 64 + m * 16 + g * 4 + r;
                float y = acc[m][n][r] + bvv;
                if constexpr (MODE == 0) {
                    int b_ = nrow >> 10, s = nrow & 1023, h_ = o >> 6, d = o & 63;
                    ((u16*)Yv)[(((size_t)b_ * HH + h_) * SS + s) * DD + d] = bfc(y * 0.125f);
                } else if constexpr (MODE == 1) {
                    int b_ = nrow >> 10, s = nrow & 1023, h_ = o >> 6, d = o & 63;
                    ((u16*)Yv)[(((size_t)b_ * HH + h_) * SS + s) * DD + d] = bfc(y);
                } else if constexpr (MODE == 2) {
                    int b_ = nrow >> 10, s = nrow & 1023, h_ = o >> 6, d = o & 63;
                    ((u16*)Yv)[(((size_t)b_ * HH + h_) * DD + d) * SS + s] = bfc(y);
                } else {
                    ((float*)Yv)[(size_t)nrow * HSZ + o] = y;
                }
            }
        }
    }
}

// ---------------------------------------------------------------------------
// Attention, flash-style. Block = (128 queries, one (b,h)); 4 waves; each wave
// owns 32 queries and streams ALL 1024 keys in 16 chunks of 64 (no cross-wave
// merge). Swapped QK^T (mfma(K,Q)) keeps each query's scores lane-local
// (query = l15); online softmax with defer-max THR=8; per-wave padded LDS
// buffer transposes P~ (key-major -> query-major) for the PV A-operand.
// K double-buffered in regs, V single-buffered; 16 loads in flight per chunk.
// ---------------------------------------------------------------------------
__global__ __launch_bounds__(256) void attn_kernel(const u16* __restrict__ Qh,
                                                   const u16* __restrict__ Kh,
                                                   const u16* __restrict__ Vt,
                                                   const float* __restrict__ bias,
                                                   u16* __restrict__ ctx) {
    const int qt = blockIdx.x;   // 0..7
    const int h  = blockIdx.y;   // 0..15
    const int b  = blockIdx.z;   // 0..7
    const int bh = b * HH + h;

    const int tid  = threadIdx.x;
    const int wave = tid >> 6;
    const int lane = tid & 63;
    const int l15  = lane & 15;
    const int g    = lane >> 4;
    const int qw0  = qt * 128 + wave * 32;   // first query of this wave

    __shared__ float bias_s[SS];             // 4 KB
    __shared__ u16   Pw[4][16][72];          // 9 KB, stride 72 -> 2-way banks (free)

    {
        const float* br = bias + b * SS;
        *(f32x4*)&bias_s[tid * 4] = *(const f32x4*)&br[tid * 4];
    }
    __syncthreads();

    const u16* Qb = Qh + ((size_t)bh * SS + qw0) * DD;
    const u16* Kb = Kh + (size_t)bh * SS * DD;
    const u16* Vb = Vt + (size_t)bh * DD * SS;

    // Q fragments: qf[qq][half] supplies Q[qw0+qq*16+l15][half*32 + g*8 ..+8]
    bf16x8 qf[2][2];
#pragma unroll
    for (int qq = 0; qq < 2; ++qq)
#pragma unroll
        for (int hh = 0; hh < 2; ++hh)
            qf[qq][hh] = *(const bf16x8*)&Qb[(size_t)(qq * 16 + l15) * DD + hh * 32 + g * 8];

    f32x4 o[2][4] = {};                       // [qq][dt]; query = qq*16+g*4+r, d = dt*16+l15
    float mrun[2] = { -3e38f, -3e38f };
    float lrun[2] = { 0.0f, 0.0f };

    bf16x8 kb[2][8];                          // K frags: [buf][kt*2+half], keys kt*16+l15
#pragma unroll
    for (int kt = 0; kt < 4; ++kt)
#pragma unroll
        for (int hh = 0; hh < 2; ++hh)
            kb[0][kt * 2 + hh] = *(const bf16x8*)&Kb[(size_t)(kt * 16 + l15) * DD + hh * 32 + g * 8];

#pragma unroll 2
    for (int c = 0; c < 16; ++c) {
        const int cur = c & 1, nxt = cur ^ 1;
        const int c0  = c * 64;

        // V(c): vb[dt*2+kh] = Vt[dt*16+l15][c0 + kh*32 + g*8 ..+8]
        bf16x8 vb[8];
#pragma unroll
        for (int dt = 0; dt < 4; ++dt)
#pragma unroll
            for (int kh = 0; kh < 2; ++kh)
                vb[dt * 2 + kh] = *(const bf16x8*)&Vb[(size_t)(dt * 16 + l15) * SS + c0 + kh * 32 + g * 8];

        // K(c+1) prefetch (c=15: harmless reload of chunk 15)
        const int cn0 = (c < 15) ? c0 + 64 : c0;
#pragma unroll
        for (int kt = 0; kt < 4; ++kt)
#pragma unroll
            for (int hh = 0; hh < 2; ++hh)
                kb[nxt][kt * 2 + hh] =
                    *(const bf16x8*)&Kb[(size_t)(cn0 + kt * 16 + l15) * DD + hh * 32 + g * 8];

#pragma unroll
        for (int qq = 0; qq < 2; ++qq) {
            // QK^T (swapped): s[kt][r] = score(key c0+kt*16+g*4+r, query qw0+qq*16+l15)
            f32x4 s[4];
#pragma unroll
            for (int kt = 0; kt < 4; ++kt) {
                f32x4 a = {};
                a = __builtin_amdgcn_mfma_f32_16x16x32_bf16(kb[cur][kt * 2 + 0], qf[qq][0], a, 0, 0, 0);
                a = __builtin_amdgcn_mfma_f32_16x16x32_bf16(kb[cur][kt * 2 + 1], qf[qq][1], a, 0, 0, 0);
                s[kt] = a;
            }
            // bias + chunk max (per query l15; keys spread over kt, g, r)
            float pm = -3e38f;
#pragma unroll
            for (int kt = 0; kt < 4; ++kt)
#pragma unroll
                for (int r = 0; r < 4; ++r) {
                    s[kt][r] += bias_s[c0 + kt * 16 + g * 4 + r];
                    pm = fmaxf(pm, s[kt][r]);
                }
            pm = fmaxf(pm, __shfl_xor(pm, 16));
            pm = fmaxf(pm, __shfl_xor(pm, 32));

            // defer-max: rescale only when max grows past THR=8 (wave-uniform)
            if (!__all(pm <= mrun[qq] + 8.0f)) {
                float sc = __expf(mrun[qq] - pm);   // first chunk: exp(-huge)=0
                mrun[qq] = pm;
                lrun[qq] *= sc;
                float f0 = __shfl(sc, g * 4 + 0);
                float f1 = __shfl(sc, g * 4 + 1);
                float f2 = __shfl(sc, g * 4 + 2);
                float f3 = __shfl(sc, g * 4 + 3);
#pragma unroll
                for (int dt = 0; dt < 4; ++dt) {
                    o[qq][dt][0] *= f0; o[qq][dt][1] *= f1;
                    o[qq][dt][2] *= f2; o[qq][dt][3] *= f3;
                }
            }

            // P~ = exp(s - mrun) -> bf16 LDS (query-major), accumulate l
            float ls = 0.0f;
#pragma unroll
            for (int kt = 0; kt < 4; ++kt) {
                union { u16x4 v; u16 u[4]; } pv;
#pragma unroll
                for (int r = 0; r < 4; ++r) {
                    float e = __expf(s[kt][r] - mrun[qq]);
                    ls += e;
                    pv.u[r] = bfc(e);
                }
                *(u16x4*)&Pw[wave][l15][kt * 16 + g * 4] = pv.v;
            }
            ls += __shfl_xor(ls, 16);
            ls += __shfl_xor(ls, 32);
            lrun[qq] += ls;

            // PV: O[q][d] += P~ . V  (A = P query-major from LDS, B = Vt rows)
#pragma unroll
            for (int kh = 0; kh < 2; ++kh) {
                bf16x8 pa = *(const bf16x8*)&Pw[wave][l15][kh * 32 + g * 8];
#pragma unroll
                for (int dt = 0; dt < 4; ++dt)
                    o[qq][dt] = __builtin_amdgcn_mfma_f32_16x16x32_bf16(pa, vb[dt * 2 + kh], o[qq][dt], 0, 0, 0);
            }
        }
    }

    // ---- epilogue: normalize by l (per query), write ctx bf16 ----
#pragma unroll
    for (int qq = 0; qq < 2; ++qq) {
        float inv = 1.0f / lrun[qq];           // valid for query l15 (uniform over g)
        float i0 = __shfl(inv, g * 4 + 0);
        float i1 = __shfl(inv, g * 4 + 1);
        float i2 = __shfl(inv, g * 4 + 2);
        float i3 = __shfl(inv, g * 4 + 3);
#pragma unroll
        for (int dt = 0; dt < 4; ++dt) {
            const int col = h * DD + dt * 16 + l15;
            const int qr  = b * SS + qw0 + qq * 16 + g * 4;
            ctx[(size_t)(qr + 0) * HSZ + col] = bfc(o[qq][dt][0] * i0);
            ctx[(size_t)(qr + 1) * HSZ + col] = bfc(o[qq][dt][1] * i1);
            ctx[(size_t)(qr + 2) * HSZ + col] = bfc(o[qq][dt][2] * i2);
            ctx[(size_t)(qr + 3) * HSZ + col] = bfc(o[qq][dt][3] * i3);
        }
    }
}

// ---------------------------------------------------------------------------
extern "C" void kernel_launch(void* const* d_in, const int* in_sizes, int n_in,
                              void* d_out, int out_size, void* d_ws, size_t ws_size,
                              hipStream_t stream) {
    const float* v    = (const float*)d_in[0];
    const float* k    = (const float*)d_in[1];
    const float* q    = (const float*)d_in[2];
    const void*  mask = d_in[3];
    const float* Wq = (const float*)d_in[4];
    const float* bq = (const float*)d_in[5];
    const float* Wk = (const float*)d_in[6];
    const float* bk = (const float*)d_in[7];
    const float* Wv = (const float*)d_in[8];
    const float* bv = (const float*)d_in[9];
    const float* Wo = (const float*)d_in[10];
    const float* bo = (const float*)d_in[11];

    char* ws = (char*)d_ws;
    float* bias = (float*)ws;                       // 32 KB
    u16*   Qh   = (u16*)(ws + 65536);               // 16 MB each
    u16*   Kh   = Qh + (size_t)BB * HH * SS * DD;
    u16*   Vt   = Kh + (size_t)BB * HH * SS * DD;
    u16*   ctx  = Vt + (size_t)BB * HH * SS * DD;

    mask_bias_kernel<<<1, 1024, 0, stream>>>(mask, bias);

    dim3 pgrid(NTOK / 128, HSZ / 128);   // (64, 8)
    proj_kernel<0><<<pgrid, 256, 0, stream>>>(q, Wq, bq, Qh);
    proj_kernel<1><<<pgrid, 256, 0, stream>>>(k, Wk, bk, Kh);
    proj_kernel<2><<<pgrid, 256, 0, stream>>>(v, Wv, bv, Vt);

    dim3 agrid(SS / 128, HH, BB);        // (8, 16, 8)
    attn_kernel<<<agrid, 256, 0, stream>>>(Qh, Kh, Vt, bias, ctx);

    proj_kernel<3><<<pgrid, 256, 0, stream>>>(ctx, Wo, bo, (float*)d_out);
}

// Round 5
// 242.141 us; speedup vs baseline: 2.1148x; 1.1365x over previous
//
#include <hip/hip_runtime.h>
#include <hip/hip_bf16.h>

// Problem constants
#define HH   16
#define DD   64
#define HSZ  1024
#define BB   8
#define SS   1024
#define NTOK (BB*SS)   // 8192
#define LOG2E 1.4426950408889634f

typedef __attribute__((ext_vector_type(8))) short bf16x8;
typedef __attribute__((ext_vector_type(4))) float f32x4;
typedef unsigned short u16;
typedef __attribute__((ext_vector_type(4))) unsigned short u16x4;

__device__ __forceinline__ u16 bfc(float x) {
    __hip_bfloat16 h = __float2bfloat16(x);   // RNE; pairs into v_cvt_pk_bf16_f32
    return *(u16*)&h;
}

// 2^x via v_exp_f32 (native exp2). __exp2f is not declared on this toolchain.
__device__ __forceinline__ float exp2fast(float x) {
    return __builtin_amdgcn_exp2f(x);
}

// async global->LDS, 16B per lane. LDS dest is WAVE-UNIFORM base + lane*16 (m104);
// global src is per-lane.
__device__ __forceinline__ void gload16(const u16* g, u16* l) {
    __builtin_amdgcn_global_load_lds(
        (const __attribute__((address_space(1))) void*)g,
        (__attribute__((address_space(3))) void*)l, 16, 0, 0);
}

// ---------------------------------------------------------------------------
// Mask -> additive bias in log2e units (scores are pre-scaled by log2e so
// softmax exp becomes exp2). bias = mask ? -1e9*log2e : 0.
// Format detection: int32 bool => bytes at idx%4!=0 are all zero.
// ---------------------------------------------------------------------------
__global__ void mask_bias_kernel(const void* mask, float* bias) {
    __shared__ int fmt;
    const unsigned char* mb = (const unsigned char*)mask;
    if (threadIdx.x == 0) fmt = 0;
    __syncthreads();
    int nz = 0;
    for (int i = threadIdx.x; i < BB * SS; i += blockDim.x)
        if ((i & 3) && mb[i]) nz = 1;
    if (nz) fmt = 1;      // benign race: all writers store 1
    __syncthreads();
    const int f = fmt;
    for (int i = threadIdx.x; i < BB * SS; i += blockDim.x) {
        bool m = f ? (mb[i] != 0) : (((const int*)mask)[i] != 0);
        bias[i] = m ? (-1e9f * LOG2E) : 0.0f;
    }
}

// ---------------------------------------------------------------------------
// f32 -> bf16 bulk convert (8 elems/thread/iter, grid-stride)
// ---------------------------------------------------------------------------
__global__ __launch_bounds__(256) void cvt_kernel(const float* __restrict__ src,
                                                  u16* __restrict__ dst, int n8) {
    int i = blockIdx.x * blockDim.x + threadIdx.x;
    const int stride = gridDim.x * blockDim.x;
    for (; i < n8; i += stride) {
        f32x4 a = *(const f32x4*)&src[(size_t)i * 8];
        f32x4 b = *(const f32x4*)&src[(size_t)i * 8 + 4];
        union { bf16x8 v; u16 u[8]; } t;
#pragma unroll
        for (int e = 0; e < 4; ++e) { t.u[e] = bfc(a[e]); t.u[4 + e] = bfc(b[e]); }
        *(bf16x8*)&dst[(size_t)i * 8] = t.v;
    }
}

// ---------------------------------------------------------------------------
// Projection GEMM: Y = X(bf16) @ W(f32->bf16)^T + b.  M=8192, N=1024, K=1024.
// BM=BN=128, BK=32, 256 threads = 4 waves (2x2), 4x4 frags/wave.
// X tile staged via global_load_lds (16B, linear LDS); W tile reg-staged+cvt.
// MODE 0: Q -> bf16 [B,H,S,D], scaled by (1/8)*log2e (folds 1/sqrt(D) and exp2)
// MODE 1: K -> bf16 [B,H,S,D]
// MODE 2: V -> bf16 [B,H,D,S]  (transposed: PV B-frag reads contiguous)
// MODE 3: ctx(bf16) @ Wo^T + bo -> f32 [B,S,HS] (d_out)
// ---------------------------------------------------------------------------
template<int MODE>
__global__ __launch_bounds__(256) void proj_kernel(const u16* __restrict__ X,
                                                   const float* __restrict__ W,
                                                   const float* __restrict__ bias,
                                                   void* __restrict__ Yv) {
    const int bm = blockIdx.x;
    const int bn = blockIdx.y;
    const int tid  = threadIdx.x;
    const int wave = tid >> 6;
    const int lane = tid & 63;
    const int l15  = lane & 15;
    const int g    = lane >> 4;
    const int wr   = wave >> 1;
    const int wc   = wave & 1;

    __shared__ u16 Xs[128 * 32];   // 8 KB, linear row-major (gload_lds dest)
    __shared__ u16 Ws[128][32];    // 8 KB

    f32x4 acc[4][4] = {};

    // gload geometry: issue i covers 16B slots [wave*128 + i*64 .. +64)
    const int slot0 = wave * 128 + lane;         // +64*i
    const int r0 = tid >> 2;        // W staging: rows
    const int c8 = (tid & 3) * 8;

    for (int k0 = 0; k0 < HSZ; k0 += 32) {
        // ---- X tile via global_load_lds ----
#pragma unroll
        for (int i = 0; i < 2; ++i) {
            const int slot = slot0 + i * 64;
            const int row = slot >> 2, cs = slot & 3;
            gload16(&X[(size_t)(bm * 128 + row) * HSZ + k0 + cs * 8],
                    &Xs[(wave * 2 + i) * 512]);
        }
        // ---- W tile reg-staged f32 -> bf16 ----
#pragma unroll
        for (int half = 0; half < 2; ++half) {
            const int row = r0 + half * 64;
            size_t base = (size_t)(bn * 128 + row) * HSZ + k0 + c8;
            f32x4 w0 = *(const f32x4*)&W[base];
            f32x4 w1 = *(const f32x4*)&W[base + 4];
            union { bf16x8 v; u16 s[8]; } t;
#pragma unroll
            for (int e = 0; e < 4; ++e) { t.s[e] = bfc(w0[e]); t.s[4 + e] = bfc(w1[e]); }
            *(bf16x8*)&Ws[row][c8] = t.v;
        }
        __syncthreads();   // drains vmcnt (gload) + lgkmcnt (ds_write)

        bf16x8 a[4], bb[4];
#pragma unroll
        for (int m = 0; m < 4; ++m)
            a[m] = *(const bf16x8*)&Xs[(wr * 64 + m * 16 + l15) * 32 + g * 8];
#pragma unroll
        for (int n = 0; n < 4; ++n)
            bb[n] = *(const bf16x8*)&Ws[wc * 64 + n * 16 + l15][g * 8];
#pragma unroll
        for (int m = 0; m < 4; ++m)
#pragma unroll
            for (int n = 0; n < 4; ++n)
                acc[m][n] = __builtin_amdgcn_mfma_f32_16x16x32_bf16(a[m], bb[n], acc[m][n], 0, 0, 0);
        __syncthreads();
    }

    // ---- epilogue ----
#pragma unroll
    for (int m = 0; m < 4; ++m) {
#pragma unroll
        for (int n = 0; n < 4; ++n) {
            const int o = bn * 128 + wc * 64 + n * 16 + l15;
            const float bvv = bias[o];
#pragma unroll
            for (int r = 0; r < 4; ++r) {
                const int nrow = bm * 128 + wr * 64 + m * 16 + g * 4 + r;
                float y = acc[m][n][r] + bvv;
                if constexpr (MODE == 0) {
                    int b_ = nrow >> 10, s = nrow & 1023, h_ = o >> 6, d = o & 63;
                    ((u16*)Yv)[(((size_t)b_ * HH + h_) * SS + s) * DD + d] = bfc(y * (0.125f * LOG2E));
                } else if constexpr (MODE == 1) {
                    int b_ = nrow >> 10, s = nrow & 1023, h_ = o >> 6, d = o & 63;
                    ((u16*)Yv)[(((size_t)b_ * HH + h_) * SS + s) * DD + d] = bfc(y);
                } else if constexpr (MODE == 2) {
                    int b_ = nrow >> 10, s = nrow & 1023, h_ = o >> 6, d = o & 63;
                    ((u16*)Yv)[(((size_t)b_ * HH + h_) * DD + d) * SS + s] = bfc(y);
                } else {
                    ((float*)Yv)[(size_t)nrow * HSZ + o] = y;
                }
            }
        }
    }
}

// ---------------------------------------------------------------------------
// Attention, flash-style. Block = (256 queries, one (b,h)); 4 waves; each wave
// owns 64 queries (4 qq-tiles of 16) and streams all 1024 keys in 16 chunks of
// 64. Swapped QK^T keeps scores lane-local (query = l15); online softmax with
// defer-max (THR = 8*log2e); exp2 (log2e folded into Q and mask bias).
// K frags double-buffered in regs; P~ transposed through per-(wave,qq-parity)
// padded LDS buffers.
// ---------------------------------------------------------------------------
__global__ __launch_bounds__(256) void attn_kernel(const u16* __restrict__ Qh,
                                                   const u16* __restrict__ Kh,
                                                   const u16* __restrict__ Vt,
                                                   const float* __restrict__ bias,
                                                   u16* __restrict__ ctx) {
    const int qt = blockIdx.x;   // 0..3
    const int h  = blockIdx.y;   // 0..15
    const int b  = blockIdx.z;   // 0..7
    const int bh = b * HH + h;

    const int tid  = threadIdx.x;
    const int wave = tid >> 6;
    const int lane = tid & 63;
    const int l15  = lane & 15;
    const int g    = lane >> 4;
    const int qw0  = qt * 256 + wave * 64;   // first query of this wave

    __shared__ float bias_s[SS];             // 4 KB
    __shared__ u16   Pw[4][2][16][72];       // 18 KB; stride 72 -> 2-way banks (free)

    {
        const float* br = bias + b * SS;
        *(f32x4*)&bias_s[tid * 4] = *(const f32x4*)&br[tid * 4];
    }
    __syncthreads();

    const u16* Qb = Qh + ((size_t)bh * SS + qw0) * DD;
    const u16* Kb = Kh + (size_t)bh * SS * DD;
    const u16* Vb = Vt + (size_t)bh * DD * SS;

    // Q fragments: qf[qq][half] = Q[qw0+qq*16+l15][half*32 + g*8 ..+8]
    bf16x8 qf[4][2];
#pragma unroll
    for (int qq = 0; qq < 4; ++qq)
#pragma unroll
        for (int hh = 0; hh < 2; ++hh)
            qf[qq][hh] = *(const bf16x8*)&Qb[(size_t)(qq * 16 + l15) * DD + hh * 32 + g * 8];

    f32x4 o[4][4] = {};                       // [qq][dt]; query = qq*16+g*4+r, d = dt*16+l15
    float mrun[4] = { -3e38f, -3e38f, -3e38f, -3e38f };
    float lrun[4] = { 0.0f, 0.0f, 0.0f, 0.0f };

    bf16x8 kb[2][8];                          // [buf][kt*2+half], key = kt*16+l15
#pragma unroll
    for (int kt = 0; kt < 4; ++kt)
#pragma unroll
        for (int hh = 0; hh < 2; ++hh)
            kb[0][kt * 2 + hh] = *(const bf16x8*)&Kb[(size_t)(kt * 16 + l15) * DD + hh * 32 + g * 8];

#pragma unroll 2
    for (int c = 0; c < 16; ++c) {
        const int cur = c & 1, nxt = cur ^ 1;
        const int c0  = c * 64;

        // V(c): vb[dt*2+kh] = Vt[dt*16+l15][c0 + kh*32 + g*8 ..+8]
        bf16x8 vb[8];
#pragma unroll
        for (int dt = 0; dt < 4; ++dt)
#pragma unroll
            for (int kh = 0; kh < 2; ++kh)
                vb[dt * 2 + kh] = *(const bf16x8*)&Vb[(size_t)(dt * 16 + l15) * SS + c0 + kh * 32 + g * 8];

        // K(c+1) prefetch (c=15: harmless reload)
        const int cn0 = (c < 15) ? c0 + 64 : c0;
#pragma unroll
        for (int kt = 0; kt < 4; ++kt)
#pragma unroll
            for (int hh = 0; hh < 2; ++hh)
                kb[nxt][kt * 2 + hh] =
                    *(const bf16x8*)&Kb[(size_t)(cn0 + kt * 16 + l15) * DD + hh * 32 + g * 8];

#pragma unroll
        for (int qq = 0; qq < 4; ++qq) {
            // QK^T (swapped): s[kt][r] = score2(key c0+kt*16+g*4+r, query qw0+qq*16+l15)
            f32x4 s[4];
#pragma unroll
            for (int kt = 0; kt < 4; ++kt) {
                f32x4 a = {};
                a = __builtin_amdgcn_mfma_f32_16x16x32_bf16(kb[cur][kt * 2 + 0], qf[qq][0], a, 0, 0, 0);
                a = __builtin_amdgcn_mfma_f32_16x16x32_bf16(kb[cur][kt * 2 + 1], qf[qq][1], a, 0, 0, 0);
                s[kt] = a;
            }
            // bias + chunk max (per query l15)
            float pm = -3e38f;
#pragma unroll
            for (int kt = 0; kt < 4; ++kt)
#pragma unroll
                for (int r = 0; r < 4; ++r) {
                    s[kt][r] += bias_s[c0 + kt * 16 + g * 4 + r];
                    pm = fmaxf(pm, s[kt][r]);
                }
            pm = fmaxf(pm, __shfl_xor(pm, 16));
            pm = fmaxf(pm, __shfl_xor(pm, 32));

            // defer-max: rescale only when max grows past 8*log2e (wave-uniform)
            if (!__all(pm <= mrun[qq] + 11.5416f)) {
                float sc = exp2fast(mrun[qq] - pm);   // first chunk: exp2(-huge)=0
                mrun[qq] = pm;
                lrun[qq] *= sc;
                float f0 = __shfl(sc, g * 4 + 0);
                float f1 = __shfl(sc, g * 4 + 1);
                float f2 = __shfl(sc, g * 4 + 2);
                float f3 = __shfl(sc, g * 4 + 3);
#pragma unroll
                for (int dt = 0; dt < 4; ++dt) {
                    o[qq][dt][0] *= f0; o[qq][dt][1] *= f1;
                    o[qq][dt][2] *= f2; o[qq][dt][3] *= f3;
                }
            }

            // P~ = exp2(s - mrun) -> bf16 LDS (transpose to query-major), local sum
            float ls = 0.0f;
#pragma unroll
            for (int kt = 0; kt < 4; ++kt) {
                union { u16x4 v; u16 u[4]; } pv;
#pragma unroll
                for (int r = 0; r < 4; ++r) {
                    float e = exp2fast(s[kt][r] - mrun[qq]);
                    ls += e;
                    pv.u[r] = bfc(e);
                }
                *(u16x4*)&Pw[wave][qq & 1][l15][kt * 16 + g * 4] = pv.v;
            }
            ls += __shfl_xor(ls, 16);
            ls += __shfl_xor(ls, 32);
            lrun[qq] += ls;

            // PV: O[q][d] += P~ . V
#pragma unroll
            for (int kh = 0; kh < 2; ++kh) {
                bf16x8 pa = *(const bf16x8*)&Pw[wave][qq & 1][l15][kh * 32 + g * 8];
#pragma unroll
                for (int dt = 0; dt < 4; ++dt)
                    o[qq][dt] = __builtin_amdgcn_mfma_f32_16x16x32_bf16(pa, vb[dt * 2 + kh], o[qq][dt], 0, 0, 0);
            }
        }
    }

    // ---- epilogue: normalize per query, write ctx bf16 ----
#pragma unroll
    for (int qq = 0; qq < 4; ++qq) {
        float inv = 1.0f / lrun[qq];           // valid for query l15 (uniform over g)
        float i0 = __shfl(inv, g * 4 + 0);
        float i1 = __shfl(inv, g * 4 + 1);
        float i2 = __shfl(inv, g * 4 + 2);
        float i3 = __shfl(inv, g * 4 + 3);
#pragma unroll
        for (int dt = 0; dt < 4; ++dt) {
            const int col = h * DD + dt * 16 + l15;
            const int qr  = b * SS + qw0 + qq * 16 + g * 4;
            ctx[(size_t)(qr + 0) * HSZ + col] = bfc(o[qq][dt][0] * i0);
            ctx[(size_t)(qr + 1) * HSZ + col] = bfc(o[qq][dt][1] * i1);
            ctx[(size_t)(qr + 2) * HSZ + col] = bfc(o[qq][dt][2] * i2);
            ctx[(size_t)(qr + 3) * HSZ + col] = bfc(o[qq][dt][3] * i3);
        }
    }
}

// ---------------------------------------------------------------------------
extern "C" void kernel_launch(void* const* d_in, const int* in_sizes, int n_in,
                              void* d_out, int out_size, void* d_ws, size_t ws_size,
                              hipStream_t stream) {
    const float* v    = (const float*)d_in[0];
    const float* k    = (const float*)d_in[1];
    const float* q    = (const float*)d_in[2];
    const void*  mask = d_in[3];
    const float* Wq = (const float*)d_in[4];
    const float* bq = (const float*)d_in[5];
    const float* Wk = (const float*)d_in[6];
    const float* bk = (const float*)d_in[7];
    const float* Wv = (const float*)d_in[8];
    const float* bv = (const float*)d_in[9];
    const float* Wo = (const float*)d_in[10];
    const float* bo = (const float*)d_in[11];

    char* ws = (char*)d_ws;
    float* bias = (float*)ws;                       // 32 KB
    u16*   xbf  = (u16*)(ws + 65536);               // 16 MB, reused: q/k/v bf16, then ctx
    u16*   Qh   = xbf + (size_t)NTOK * HSZ;         // 16 MB each
    u16*   Kh   = Qh + (size_t)NTOK * HSZ;
    u16*   Vt   = Kh + (size_t)NTOK * HSZ;
    u16*   ctx  = xbf;                              // reuse (free after proj<2>)

    const int n8 = NTOK * HSZ / 8;                  // 1048576

    mask_bias_kernel<<<1, 1024, 0, stream>>>(mask, bias);

    dim3 pgrid(NTOK / 128, HSZ / 128);   // (64, 8)
    cvt_kernel<<<2048, 256, 0, stream>>>(q, xbf, n8);
    proj_kernel<0><<<pgrid, 256, 0, stream>>>(xbf, Wq, bq, Qh);
    cvt_kernel<<<2048, 256, 0, stream>>>(k, xbf, n8);
    proj_kernel<1><<<pgrid, 256, 0, stream>>>(xbf, Wk, bk, Kh);
    cvt_kernel<<<2048, 256, 0, stream>>>(v, xbf, n8);
    proj_kernel<2><<<pgrid, 256, 0, stream>>>(xbf, Wv, bv, Vt);

    dim3 agrid(SS / 256, HH, BB);        // (4, 16, 8)
    attn_kernel<<<agrid, 256, 0, stream>>>(Qh, Kh, Vt, bias, ctx);

    proj_kernel<3><<<pgrid, 256, 0, stream>>>(ctx, Wo, bo, (float*)d_out);
}

// Round 6
// 218.497 us; speedup vs baseline: 2.3437x; 1.1082x over previous
//
#include <hip/hip_runtime.h>
#include <hip/hip_bf16.h>

// Problem constants
#define HH   16
#define DD   64
#define HSZ  1024
#define BB   8
#define SS   1024
#define NTOK (BB*SS)   // 8192
#define LOG2E 1.4426950408889634f

typedef __attribute__((ext_vector_type(8))) short bf16x8;
typedef __attribute__((ext_vector_type(4))) float f32x4;
typedef unsigned short u16;
typedef __attribute__((ext_vector_type(4))) unsigned short u16x4;

__device__ __forceinline__ u16 bfc(float x) {
    __hip_bfloat16 h = __float2bfloat16(x);   // RNE; pairs into v_cvt_pk_bf16_f32
    return *(u16*)&h;
}

// 2^x via v_exp_f32 (native exp2). __exp2f is not declared on this toolchain.
__device__ __forceinline__ float exp2fast(float x) {
    return __builtin_amdgcn_exp2f(x);
}

// async global->LDS, 16B per lane. LDS dest is WAVE-UNIFORM base + lane*16 (m104);
// global src is per-lane.
__device__ __forceinline__ void gload16(const u16* g, u16* l) {
    __builtin_amdgcn_global_load_lds(
        (const __attribute__((address_space(1))) void*)g,
        (__attribute__((address_space(3))) void*)l, 16, 0, 0);
}

// ---------------------------------------------------------------------------
// Mask -> additive bias in log2e units (scores pre-scaled by log2e so softmax
// exp becomes exp2). bias = mask ? -1e9*log2e : 0.
// Format detection: int32 bool => bytes at idx%4!=0 are all zero.
// ---------------------------------------------------------------------------
__global__ void mask_bias_kernel(const void* mask, float* bias) {
    __shared__ int fmt;
    const unsigned char* mb = (const unsigned char*)mask;
    if (threadIdx.x == 0) fmt = 0;
    __syncthreads();
    int nz = 0;
    for (int i = threadIdx.x; i < BB * SS; i += blockDim.x)
        if ((i & 3) && mb[i]) nz = 1;
    if (nz) fmt = 1;      // benign race: all writers store 1
    __syncthreads();
    const int f = fmt;
    for (int i = threadIdx.x; i < BB * SS; i += blockDim.x) {
        bool m = f ? (mb[i] != 0) : (((const int*)mask)[i] != 0);
        bias[i] = m ? (-1e9f * LOG2E) : 0.0f;
    }
}

// ---------------------------------------------------------------------------
// Dual-region f32 -> bf16 convert (8 elems/thread/iter, grid-stride).
// Region 2 may be empty (n2 = 0, pointers unused).
// ---------------------------------------------------------------------------
__global__ __launch_bounds__(256) void cvt2_kernel(const float* __restrict__ s1,
                                                   u16* __restrict__ d1, int n1,
                                                   const float* __restrict__ s2,
                                                   u16* __restrict__ d2, int n2) {
    int i = blockIdx.x * blockDim.x + threadIdx.x;
    const int stride = gridDim.x * blockDim.x;
    const int ntot = n1 + n2;
    for (; i < ntot; i += stride) {
        const float* s; u16* d; int j;
        if (i < n1) { s = s1; d = d1; j = i; }
        else        { s = s2; d = d2; j = i - n1; }
        f32x4 a = *(const f32x4*)&s[(size_t)j * 8];
        f32x4 b = *(const f32x4*)&s[(size_t)j * 8 + 4];
        union { bf16x8 v; u16 u[8]; } t;
#pragma unroll
        for (int e = 0; e < 4; ++e) { t.u[e] = bfc(a[e]); t.u[4 + e] = bfc(b[e]); }
        *(bf16x8*)&d[(size_t)j * 8] = t.v;
    }
}

// ---------------------------------------------------------------------------
// Projection GEMM: Y = X(bf16) @ W(bf16)^T + b.  M=8192, N=1024, K=1024.
// BM=BN=128, BK=32, 256 threads = 4 waves (2x2), 4x4 frags/wave.
// Both X and W tiles staged via global_load_lds (16B, linear LDS) — pure m97
// structure: 4 gload issues + 8 ds_read_b128 + 16 MFMA per wave per k-step.
// MODE 0: Q -> bf16 [B,H,S,D], scaled by (1/8)*log2e (folds 1/sqrt(D) + exp2)
// MODE 1: K -> bf16 [B,H,S,D]
// MODE 2: V -> bf16 [B,H,D,S]  (transposed: PV B-frag reads contiguous)
// MODE 3: ctx(bf16) @ Wo^T + bo -> f32 [B,S,HS] (d_out)
// ---------------------------------------------------------------------------
template<int MODE>
__global__ __launch_bounds__(256) void proj_kernel(const u16* __restrict__ X,
                                                   const u16* __restrict__ W,
                                                   const float* __restrict__ bias,
                                                   void* __restrict__ Yv) {
    const int bm = blockIdx.x;
    const int bn = blockIdx.y;
    const int tid  = threadIdx.x;
    const int wave = tid >> 6;
    const int lane = tid & 63;
    const int l15  = lane & 15;
    const int g    = lane >> 4;
    const int wr   = wave >> 1;
    const int wc   = wave & 1;

    __shared__ u16 Xs[128 * 32];   // 8 KB, linear row-major (gload_lds dest)
    __shared__ u16 Ws[128 * 32];   // 8 KB

    f32x4 acc[4][4] = {};

    // gload geometry: issue i covers 16B slots [wave*128 + i*64 .. +64)
    const int slot0 = wave * 128 + lane;

    for (int k0 = 0; k0 < HSZ; k0 += 32) {
#pragma unroll
        for (int i = 0; i < 2; ++i) {
            const int slot = slot0 + i * 64;
            const int row = slot >> 2, cs = slot & 3;
            gload16(&X[(size_t)(bm * 128 + row) * HSZ + k0 + cs * 8],
                    &Xs[(wave * 2 + i) * 512]);
            gload16(&W[(size_t)(bn * 128 + row) * HSZ + k0 + cs * 8],
                    &Ws[(wave * 2 + i) * 512]);
        }
        __syncthreads();   // implicit vmcnt(0) drain completes gloads

        bf16x8 a[4], bb[4];
#pragma unroll
        for (int m = 0; m < 4; ++m)
            a[m] = *(const bf16x8*)&Xs[(wr * 64 + m * 16 + l15) * 32 + g * 8];
#pragma unroll
        for (int n = 0; n < 4; ++n)
            bb[n] = *(const bf16x8*)&Ws[(wc * 64 + n * 16 + l15) * 32 + g * 8];
#pragma unroll
        for (int m = 0; m < 4; ++m)
#pragma unroll
            for (int n = 0; n < 4; ++n)
                acc[m][n] = __builtin_amdgcn_mfma_f32_16x16x32_bf16(a[m], bb[n], acc[m][n], 0, 0, 0);
        __syncthreads();
    }

    // ---- epilogue ----
#pragma unroll
    for (int m = 0; m < 4; ++m) {
#pragma unroll
        for (int n = 0; n < 4; ++n) {
            const int o = bn * 128 + wc * 64 + n * 16 + l15;
            const float bvv = bias[o];
#pragma unroll
            for (int r = 0; r < 4; ++r) {
                const int nrow = bm * 128 + wr * 64 + m * 16 + g * 4 + r;
                float y = acc[m][n][r] + bvv;
                if constexpr (MODE == 0) {
                    int b_ = nrow >> 10, s = nrow & 1023, h_ = o >> 6, d = o & 63;
                    ((u16*)Yv)[(((size_t)b_ * HH + h_) * SS + s) * DD + d] = bfc(y * (0.125f * LOG2E));
                } else if constexpr (MODE == 1) {
                    int b_ = nrow >> 10, s = nrow & 1023, h_ = o >> 6, d = o & 63;
                    ((u16*)Yv)[(((size_t)b_ * HH + h_) * SS + s) * DD + d] = bfc(y);
                } else if constexpr (MODE == 2) {
                    int b_ = nrow >> 10, s = nrow & 1023, h_ = o >> 6, d = o & 63;
                    ((u16*)Yv)[(((size_t)b_ * HH + h_) * DD + d) * SS + s] = bfc(y);
                } else {
                    ((float*)Yv)[(size_t)nrow * HSZ + o] = y;
                }
            }
        }
    }
}

// ---------------------------------------------------------------------------
// Attention, flash-style. Block = (256 queries, one (b,h)); 4 waves; each wave
// owns 64 queries (4 qq-tiles of 16), streams all 1024 keys in 16 chunks of 64.
// Swapped QK^T keeps scores lane-local (query = l15); the mask bias depends
// only on the key = the swapped C-fragment ROW (g*4+r), so it seeds the MFMA
// C operand directly (one ds_read_b128 per kt per chunk, shared by all qq).
// Online softmax with defer-max (THR = 8*log2e); exp2 throughout.
// K frags double-buffered in regs; P~ transposed via per-(wave,parity) LDS.
// ---------------------------------------------------------------------------
__global__ __launch_bounds__(256) void attn_kernel(const u16* __restrict__ Qh,
                                                   const u16* __restrict__ Kh,
                                                   const u16* __restrict__ Vt,
                                                   const float* __restrict__ bias,
                                                   u16* __restrict__ ctx) {
    const int qt = blockIdx.x;   // 0..3
    const int h  = blockIdx.y;   // 0..15
    const int b  = blockIdx.z;   // 0..7
    const int bh = b * HH + h;

    const int tid  = threadIdx.x;
    const int wave = tid >> 6;
    const int lane = tid & 63;
    const int l15  = lane & 15;
    const int g    = lane >> 4;
    const int qw0  = qt * 256 + wave * 64;   // first query of this wave

    __shared__ float bias_s[SS];             // 4 KB
    __shared__ u16   Pw[4][2][16][72];       // 18 KB; stride 72 -> 2-way banks (free)

    {
        const float* br = bias + b * SS;
        *(f32x4*)&bias_s[tid * 4] = *(const f32x4*)&br[tid * 4];
    }
    __syncthreads();

    const u16* Qb = Qh + ((size_t)bh * SS + qw0) * DD;
    const u16* Kb = Kh + (size_t)bh * SS * DD;
    const u16* Vb = Vt + (size_t)bh * DD * SS;

    // Q fragments: qf[qq][half] = Q[qw0+qq*16+l15][half*32 + g*8 ..+8]
    bf16x8 qf[4][2];
#pragma unroll
    for (int qq = 0; qq < 4; ++qq)
#pragma unroll
        for (int hh = 0; hh < 2; ++hh)
            qf[qq][hh] = *(const bf16x8*)&Qb[(size_t)(qq * 16 + l15) * DD + hh * 32 + g * 8];

    f32x4 o[4][4] = {};                       // [qq][dt]; query = qq*16+g*4+r, d = dt*16+l15
    float mrun[4] = { -3e38f, -3e38f, -3e38f, -3e38f };
    float lrun[4] = { 0.0f, 0.0f, 0.0f, 0.0f };

    bf16x8 kb[2][8];                          // [buf][kt*2+half], key = kt*16+l15
#pragma unroll
    for (int kt = 0; kt < 4; ++kt)
#pragma unroll
        for (int hh = 0; hh < 2; ++hh)
            kb[0][kt * 2 + hh] = *(const bf16x8*)&Kb[(size_t)(kt * 16 + l15) * DD + hh * 32 + g * 8];

#pragma unroll 2
    for (int c = 0; c < 16; ++c) {
        const int cur = c & 1, nxt = cur ^ 1;
        const int c0  = c * 64;

        // V(c): vb[dt*2+kh] = Vt[dt*16+l15][c0 + kh*32 + g*8 ..+8]
        bf16x8 vb[8];
#pragma unroll
        for (int dt = 0; dt < 4; ++dt)
#pragma unroll
            for (int kh = 0; kh < 2; ++kh)
                vb[dt * 2 + kh] = *(const bf16x8*)&Vb[(size_t)(dt * 16 + l15) * SS + c0 + kh * 32 + g * 8];

        // K(c+1) prefetch (c=15: harmless reload)
        const int cn0 = (c < 15) ? c0 + 64 : c0;
#pragma unroll
        for (int kt = 0; kt < 4; ++kt)
#pragma unroll
            for (int hh = 0; hh < 2; ++hh)
                kb[nxt][kt * 2 + hh] =
                    *(const bf16x8*)&Kb[(size_t)(cn0 + kt * 16 + l15) * DD + hh * 32 + g * 8];

        // bias seeds for this chunk: bseed[kt][r] = bias(key c0+kt*16+g*4+r),
        // shared by all qq (matches swapped C/D layout: row = key, col = query)
        f32x4 bseed[4];
#pragma unroll
        for (int kt = 0; kt < 4; ++kt)
            bseed[kt] = *(const f32x4*)&bias_s[c0 + kt * 16 + g * 4];

#pragma unroll
        for (int qq = 0; qq < 4; ++qq) {
            // QK^T (swapped), C seeded with mask bias
            f32x4 s[4];
#pragma unroll
            for (int kt = 0; kt < 4; ++kt) {
                f32x4 a = bseed[kt];
                a = __builtin_amdgcn_mfma_f32_16x16x32_bf16(kb[cur][kt * 2 + 0], qf[qq][0], a, 0, 0, 0);
                a = __builtin_amdgcn_mfma_f32_16x16x32_bf16(kb[cur][kt * 2 + 1], qf[qq][1], a, 0, 0, 0);
                s[kt] = a;
            }
            // chunk max (tree; per query l15)
            float pmk[4];
#pragma unroll
            for (int kt = 0; kt < 4; ++kt)
                pmk[kt] = fmaxf(fmaxf(s[kt][0], s[kt][1]), fmaxf(s[kt][2], s[kt][3]));
            float pm = fmaxf(fmaxf(pmk[0], pmk[1]), fmaxf(pmk[2], pmk[3]));
            pm = fmaxf(pm, __shfl_xor(pm, 16));
            pm = fmaxf(pm, __shfl_xor(pm, 32));

            // defer-max: rescale only when max grows past 8*log2e (wave-uniform)
            if (!__all(pm <= mrun[qq] + 11.5416f)) {
                float sc = exp2fast(mrun[qq] - pm);   // first chunk: exp2(-huge)=0
                mrun[qq] = pm;
                lrun[qq] *= sc;
                float f0 = __shfl(sc, g * 4 + 0);
                float f1 = __shfl(sc, g * 4 + 1);
                float f2 = __shfl(sc, g * 4 + 2);
                float f3 = __shfl(sc, g * 4 + 3);
#pragma unroll
                for (int dt = 0; dt < 4; ++dt) {
                    o[qq][dt][0] *= f0; o[qq][dt][1] *= f1;
                    o[qq][dt][2] *= f2; o[qq][dt][3] *= f3;
                }
            }

            // P~ = exp2(s - mrun) -> bf16 LDS (transpose to query-major), local sum
            float ls = 0.0f;
#pragma unroll
            for (int kt = 0; kt < 4; ++kt) {
                union { u16x4 v; u16 u[4]; } pv;
#pragma unroll
                for (int r = 0; r < 4; ++r) {
                    float e = exp2fast(s[kt][r] - mrun[qq]);
                    ls += e;
                    pv.u[r] = bfc(e);
                }
                *(u16x4*)&Pw[wave][qq & 1][l15][kt * 16 + g * 4] = pv.v;
            }
            ls += __shfl_xor(ls, 16);
            ls += __shfl_xor(ls, 32);
            lrun[qq] += ls;

            // PV: O[q][d] += P~ . V
#pragma unroll
            for (int kh = 0; kh < 2; ++kh) {
                bf16x8 pa = *(const bf16x8*)&Pw[wave][qq & 1][l15][kh * 32 + g * 8];
#pragma unroll
                for (int dt = 0; dt < 4; ++dt)
                    o[qq][dt] = __builtin_amdgcn_mfma_f32_16x16x32_bf16(pa, vb[dt * 2 + kh], o[qq][dt], 0, 0, 0);
            }
        }
    }

    // ---- epilogue: normalize per query, write ctx bf16 ----
#pragma unroll
    for (int qq = 0; qq < 4; ++qq) {
        float inv = 1.0f / lrun[qq];           // valid for query l15 (uniform over g)
        float i0 = __shfl(inv, g * 4 + 0);
        float i1 = __shfl(inv, g * 4 + 1);
        float i2 = __shfl(inv, g * 4 + 2);
        float i3 = __shfl(inv, g * 4 + 3);
#pragma unroll
        for (int dt = 0; dt < 4; ++dt) {
            const int col = h * DD + dt * 16 + l15;
            const int qr  = b * SS + qw0 + qq * 16 + g * 4;
            ctx[(size_t)(qr + 0) * HSZ + col] = bfc(o[qq][dt][0] * i0);
            ctx[(size_t)(qr + 1) * HSZ + col] = bfc(o[qq][dt][1] * i1);
            ctx[(size_t)(qr + 2) * HSZ + col] = bfc(o[qq][dt][2] * i2);
            ctx[(size_t)(qr + 3) * HSZ + col] = bfc(o[qq][dt][3] * i3);
        }
    }
}

// ---------------------------------------------------------------------------
extern "C" void kernel_launch(void* const* d_in, const int* in_sizes, int n_in,
                              void* d_out, int out_size, void* d_ws, size_t ws_size,
                              hipStream_t stream) {
    const float* v    = (const float*)d_in[0];
    const float* k    = (const float*)d_in[1];
    const float* q    = (const float*)d_in[2];
    const void*  mask = d_in[3];
    const float* Wq = (const float*)d_in[4];
    const float* bq = (const float*)d_in[5];
    const float* Wk = (const float*)d_in[6];
    const float* bk = (const float*)d_in[7];
    const float* Wv = (const float*)d_in[8];
    const float* bv = (const float*)d_in[9];
    const float* Wo = (const float*)d_in[10];
    const float* bo = (const float*)d_in[11];

    char* ws = (char*)d_ws;
    float* bias = (float*)ws;                       // 64 KB reserved
    u16*   wbf  = (u16*)(ws + 65536);               // 2 MB, reused per projection
    u16*   xbf  = (u16*)(ws + 65536 + 2097152);     // 16 MB, reused q/k/v, then ctx
    u16*   Qh   = xbf + (size_t)NTOK * HSZ;         // 16 MB each
    u16*   Kh   = Qh + (size_t)NTOK * HSZ;
    u16*   Vt   = Kh + (size_t)NTOK * HSZ;
    u16*   ctx  = xbf;                              // reuse (free after proj<2>)

    const int NX8 = NTOK * HSZ / 8;                 // 1048576
    const int NW8 = HSZ * HSZ / 8;                  // 131072

    mask_bias_kernel<<<1, 1024, 0, stream>>>(mask, bias);

    dim3 pgrid(NTOK / 128, HSZ / 128);   // (64, 8)
    cvt2_kernel<<<2048, 256, 0, stream>>>(q, xbf, NX8, Wq, wbf, NW8);
    proj_kernel<0><<<pgrid, 256, 0, stream>>>(xbf, wbf, bq, Qh);
    cvt2_kernel<<<2048, 256, 0, stream>>>(k, xbf, NX8, Wk, wbf, NW8);
    proj_kernel<1><<<pgrid, 256, 0, stream>>>(xbf, wbf, bk, Kh);
    cvt2_kernel<<<2048, 256, 0, stream>>>(v, xbf, NX8, Wv, wbf, NW8);
    proj_kernel<2><<<pgrid, 256, 0, stream>>>(xbf, wbf, bv, Vt);
    cvt2_kernel<<<512, 256, 0, stream>>>(Wo, wbf, NW8, (const float*)nullptr, (u16*)nullptr, 0);

    dim3 agrid(SS / 256, HH, BB);        // (4, 16, 8)
    attn_kernel<<<agrid, 256, 0, stream>>>(Qh, Kh, Vt, bias, ctx);

    proj_kernel<3><<<pgrid, 256, 0, stream>>>(ctx, wbf, bo, (float*)d_out);
}